// Round 10
// baseline (126.064 us; speedup 1.0000x reference)
//
#include <hip/hip_runtime.h>

// NEUROPULS unitary mesh, N=256 — R13: log-depth tree over stages.
// 11 rounds of evidence: per-stage latency has a ~150-300cy floor invariant
// to instruction count, memory source, VGPR budget, wave count, prefetch
// depth. The shared structure is 128 serially-dependent stages on one
// wave. Fix by associativity: M = D129 * G7*...*G0, G_g = product of 16
// stage-operators (G0 folds diag(e^{i*theta0})).
//  Phase 1 (group_kernel): 2048 blocks (8 groups x 256 cols) propagate
//   identity columns through 16 stages using the VERIFIED R9 machinery
//   (prep4/mstep/crossing passed R6/R9/R11/R12). Serial chain: 16 stages.
//  Phase 2 (cgemm_kernel x3): 7 dense 256x256 complex fp32 GEMMs in a
//   tree: Q_b = G(2b+1)xG(2b) [batch 4], R_b = Q(2b+1)xQ(2b) [batch 2],
//   M' = R1xR0 [batch 1, epilogue applies D129 row phase + writes planar
//   row-major output].
// All matrices column-major planar in ws: entry(r,c) at [c*256+r], im at
// +65536 floats. P(g)=g*131072, Q(b)=1048576+b*131072, R(b)=1572864+b*131072.

__device__ __forceinline__ float dpp_up1(float x) {   // wave_shr:1, n <- n-1
    return __int_as_float(__builtin_amdgcn_update_dpp(
        __float_as_int(x), __float_as_int(x), 0x138, 0xf, 0xf, false));
}
__device__ __forceinline__ float dpp_dn1(float x) {   // wave_shl:1, n <- n+1
    return __int_as_float(__builtin_amdgcn_update_dpp(
        __float_as_int(x), __float_as_int(x), 0x130, 0xf, 0xf, false));
}
__device__ __forceinline__ void sincos4(float4 th, float sn[4], float cs[4]) {
    __sincosf(th.x, &sn[0], &cs[0]);
    __sincosf(th.y, &sn[1], &cs[1]);
    __sincosf(th.z, &sn[2], &cs[2]);
    __sincosf(th.w, &sn[3], &cs[3]);
}

struct Coef { float Er[2], Ei[2], Fr[2], Fi[2], Gr[2], Gi[2]; };

// ---------- phase 1: group operators (16 stages each) ----------
__global__ __launch_bounds__(64)
void group_kernel(const float* __restrict__ thetas,  // [130,256]
                  float* __restrict__ ws)
{
    const int gid  = blockIdx.x;     // 0..2047
    const int g    = gid >> 8;       // group 0..7 -> stages 16g+1..16g+16
    const int col  = gid & 255;
    const int lane = threadIdx.x;    // 0..63

    const float U  = 0.98f * 0.505f;                  // AT^2
    const float W  = 0.98f * 0.495f;                  // AR^2
    const float Gc = 0.98f * sqrtf(0.505f * 0.495f);  // AT*AR
    const float BT = sqrtf(0.98f * 0.01f);
    const float BR = sqrtf(0.98f * 0.99f);

    float vr[4] = {0.f, 0.f, 0.f, 0.f};
    float vi[4] = {0.f, 0.f, 0.f, 0.f};

    // init: column `col` of I (g>0) or diag(exp(i*theta0)) (g==0, folds D0)
    {
        const int r0 = col - 4 * lane;
        if (0 <= r0 && r0 < 4) {
            if (g == 0) {
                float s0, c0;
                __sincosf(thetas[col], &s0, &c0);
                vr[r0] = c0; vi[r0] = s0;
            } else {
                vr[r0] = 1.f;
            }
        }
    }

    auto prep4 = [&](float4 th, Coef& K) {
        float s[4], c[4];
        sincos4(th, s, c);
        #pragma unroll
        for (int p = 0; p < 2; ++p) {
            const float c0 = c[2*p], c1 = c[2*p+1];
            const float s0 = s[2*p], s1 = s[2*p+1];
            K.Er[p] = U * c0 - W * c1;   K.Ei[p] = U * s0 - W * s1;
            K.Fr[p] = U * c1 - W * c0;   K.Fi[p] = U * s1 - W * s0;
            K.Gr[p] = -Gc * (s0 + s1);   K.Gi[p] = Gc * (c0 + c1);
        }
    };
    auto mstep = [&](const Coef& K) {
        #pragma unroll
        for (int p = 0; p < 2; ++p) {
            const int x = 2*p, y = 2*p+1;
            const float xr = vr[x], xi = vi[x], yr = vr[y], yi = vi[y];
            vr[x] = K.Er[p]*xr - K.Ei[p]*xi + K.Gr[p]*yr - K.Gi[p]*yi;
            vi[x] = K.Er[p]*xi + K.Ei[p]*xr + K.Gr[p]*yi + K.Gi[p]*yr;
            vr[y] = K.Gr[p]*xr - K.Gi[p]*xi + K.Fr[p]*yr - K.Fi[p]*yi;
            vi[y] = K.Gr[p]*xi + K.Gi[p]*xr + K.Fr[p]*yi + K.Fi[p]*yr;
        }
    };
    auto crossing = [&]() {
        float pv3r = dpp_up1(vr[3]);
        float pv3i = dpp_up1(vi[3]);
        float nv0r = dpp_dn1(vr[0]);
        float nv0i = dpp_dn1(vi[0]);
        {   // internal odd pair (4t+1, 4t+2)
            float xr = vr[1], xi = vi[1], yr = vr[2], yi = vi[2];
            vr[1] = BT*xr - BR*yi;  vi[1] = BT*xi + BR*yr;
            vr[2] = BT*yr - BR*xi;  vi[2] = BT*yi + BR*xr;
        }
        {   // pair (4t-1, 4t): lane 0 row 0 = thru
            float yr = vr[0], yi = vi[0];
            float nr = BT*yr - BR*pv3i;
            float ni = BT*yi + BR*pv3r;
            vr[0] = (lane == 0) ? BR*yr : nr;
            vi[0] = (lane == 0) ? BR*yi : ni;
        }
        {   // pair (4t+3, 4t+4): lane 63 row 255 = thru
            float xr = vr[3], xi = vi[3];
            float nr = BT*xr - BR*nv0i;
            float ni = BT*xi + BR*nv0r;
            vr[3] = (lane == 63) ? BR*xr : nr;
            vi[3] = (lane == 63) ? BR*xi : ni;
        }
    };

    // stages s = 16g+1 .. 16g+16; crossing for all s <= 127 (s=128: none)
    const float* tp = thetas + (16*g + 1) * 256 + 4 * lane;
    float4 th = *(const float4*)tp;
    for (int k = 0; k < 16; ++k) {
        float4 thn = *(const float4*)(tp + (k + 1) * 256);  // row <=129, in-bounds
        Coef K;
        prep4(th, K);
        mstep(K);
        if (16*g + 1 + k != 128) crossing();
        th = thn;
    }

    // store column col of G_g (column-major planar)
    float* base = ws + g * 131072;
    float4 re = make_float4(vr[0], vr[1], vr[2], vr[3]);
    float4 im = make_float4(vi[0], vi[1], vi[2], vi[3]);
    *(float4*)(base + col * 256 + 4 * lane)         = re;
    *(float4*)(base + 65536 + col * 256 + 4 * lane) = im;
}

// ---------- phase 2: complex GEMM, C = A x B (256x256, col-major) ----------
__global__ __launch_bounds__(256)
void cgemm_kernel(float* __restrict__ ws,
                  const float* __restrict__ thetas,
                  float* __restrict__ out,
                  int level)
{
    __shared__ float As_re[16][68], As_im[16][68];   // [row][kk], b128-friendly
    __shared__ float Bs_re[16][68], Bs_im[16][68];   // [col][kk]

    const int t  = threadIdx.x;      // 0..255
    const int bx = blockIdx.x;       // 0..255 -> 16x16 tile
    const int b  = blockIdx.y;       // batch
    const int br = bx & 15, bc = bx >> 4;
    const int tr = t & 15,  tc = t >> 4;

    const float* A; const float* B; float* C = nullptr;
    if (level == 0) {
        A = ws + (2*b + 1) * 131072;            // G(2b+1)
        B = ws + (2*b) * 131072;                // G(2b)
        C = ws + 1048576 + b * 131072;          // Q(b)
    } else if (level == 1) {
        A = ws + 1048576 + (2*b + 1) * 131072;  // Q(2b+1)
        B = ws + 1048576 + (2*b) * 131072;      // Q(2b)
        C = ws + 1572864 + b * 131072;          // R(b)
    } else {
        A = ws + 1572864 + 131072;              // R1
        B = ws + 1572864;                       // R0
    }

    const int r = br * 16 + tr;
    const int c = bc * 16 + tc;
    float accr = 0.f, acci = 0.f;

    for (int k0 = 0; k0 < 256; k0 += 64) {
        // stage A tile: rows br*16..+15 x k k0..k0+63 (1024 elems/plane)
        #pragma unroll
        for (int i = 0; i < 4; ++i) {
            const int e  = t + i * 256;
            const int rr = e & 15, kk = e >> 4;
            const int ga = (k0 + kk) * 256 + br * 16 + rr;   // A[r,k] col-major
            As_re[rr][kk] = A[ga];
            As_im[rr][kk] = A[65536 + ga];
        }
        // stage B tile: k k0..+63 x cols bc*16..+15
        #pragma unroll
        for (int i = 0; i < 4; ++i) {
            const int e  = t + i * 256;
            const int kk = e & 63, cc = e >> 6;
            const int gb = (bc * 16 + cc) * 256 + k0 + kk;   // B[k,c] col-major
            Bs_re[cc][kk] = B[gb];
            Bs_im[cc][kk] = B[65536 + gb];
        }
        __syncthreads();
        #pragma unroll 4
        for (int kk = 0; kk < 64; ++kk) {
            const float ar = As_re[tr][kk], ai = As_im[tr][kk];
            const float xr = Bs_re[tc][kk], xi = Bs_im[tc][kk];
            accr += ar * xr - ai * xi;
            acci += ar * xi + ai * xr;
        }
        __syncthreads();
    }

    if (level < 2) {
        C[c * 256 + r]         = accr;
        C[65536 + c * 256 + r] = acci;
    } else {
        // M = D129 * M'; output planar row-major re || im
        float s9, c9;
        __sincosf(thetas[129 * 256 + r], &s9, &c9);
        out[r * 256 + c]         = c9 * accr - s9 * acci;
        out[65536 + r * 256 + c] = c9 * acci + s9 * accr;
    }
}

extern "C" void kernel_launch(void* const* d_in, const int* in_sizes, int n_in,
                              void* d_out, int out_size, void* d_ws, size_t ws_size,
                              hipStream_t stream)
{
    const float* thetas = (const float*)d_in[0];   // [130,256] fp32
    float* out = (float*)d_out;                    // planar: re[65536] || im[65536]
    float* ws  = (float*)d_ws;                     // 7.34 MB used
    (void)in_sizes; (void)n_in; (void)out_size; (void)ws_size;

    group_kernel<<<dim3(2048), dim3(64), 0, stream>>>(thetas, ws);
    cgemm_kernel<<<dim3(256, 4), dim3(256), 0, stream>>>(ws, thetas, out, 0);
    cgemm_kernel<<<dim3(256, 2), dim3(256), 0, stream>>>(ws, thetas, out, 1);
    cgemm_kernel<<<dim3(256, 1), dim3(256), 0, stream>>>(ws, thetas, out, 2);
}

// Round 11
// 87.249 us; speedup vs baseline: 1.4449x; 1.4449x over previous
//
#include <hip/hip_runtime.h>

// NEUROPULS unitary mesh, N=256 — R14: G=2 stage-split + ONE reg-tiled GEMM.
// R13 post-mortem: decomposition numerics VERIFIED (absmax unchanged) but
// 7 naive cgemms (~1 TF eff) cost ~80 us. Rebalance: two 64-stage halves
// (P1 = stages 1..64 incl D0; P2 = D129 * stages 65..128) + single 256^3
// complex GEMM M = P2 x P1 (134 MFLOP). Phase 1 = R12's verified chunk
// machinery (coef kernel + 8-stage dbuf chunks + distance-2 reg pipeline),
// 512 blocks (2/CU, 48 KB LDS both resident): wall ~= 64 x 240ns ~= 15.5us.
// GEMM: 32x32 tile/block, 2x2/thread, K-chunks of 32, padded LDS (stride
// 36: float4-write-aligned, float2-read conflict-free), 16 FMA per 4 LDS
// reads -> issue-bound ~6 us on 64 blocks.
// ws layout (floats): coefs[98304] | P1 @98304 | P2 @229376 (col-major
// planar: re[col*256+row], im +65536).

__device__ __forceinline__ float dpp_up1(float x) {   // wave_shr:1, n <- n-1
    return __int_as_float(__builtin_amdgcn_update_dpp(
        __float_as_int(x), __float_as_int(x), 0x138, 0xf, 0xf, false));
}
__device__ __forceinline__ float dpp_dn1(float x) {   // wave_shl:1, n <- n+1
    return __int_as_float(__builtin_amdgcn_update_dpp(
        __float_as_int(x), __float_as_int(x), 0x130, 0xf, 0xf, false));
}
__device__ __forceinline__ void sincos4(float4 th, float sn[4], float cs[4]) {
    __sincosf(th.x, &sn[0], &cs[0]);
    __sincosf(th.y, &sn[1], &cs[1]);
    __sincosf(th.z, &sn[2], &cs[2]);
    __sincosf(th.w, &sn[3], &cs[3]);
}

// ---------- kernel 1: per-stage collapsed coefficients (R12, verified) ----
__global__ __launch_bounds__(64)
void coef_kernel(const float* __restrict__ thetas,  // [130,256]
                 float* __restrict__ coefs)         // 128*3*64 float4
{
    const int s0   = blockIdx.x;    // 0..127 -> theta row s0+1
    const int lane = threadIdx.x;   // 0..63

    const float U  = 0.98f * 0.505f;                  // AT^2
    const float W  = 0.98f * 0.495f;                  // AR^2
    const float Gc = 0.98f * sqrtf(0.505f * 0.495f);  // AT*AR

    float4 th = *(const float4*)(thetas + (s0 + 1) * 256 + 4 * lane);
    float s[4], c[4];
    sincos4(th, s, c);

    float4 A, B, C;
    A.x = U * c[0] - W * c[1];   A.y = U * s[0] - W * s[1];   // E0
    A.z = U * c[1] - W * c[0];   A.w = U * s[1] - W * s[0];   // F0
    B.x = -Gc * (s[0] + s[1]);   B.y = Gc * (c[0] + c[1]);    // G0
    B.z = -Gc * (s[2] + s[3]);   B.w = Gc * (c[2] + c[3]);    // G1
    C.x = U * c[2] - W * c[3];   C.y = U * s[2] - W * s[3];   // E1
    C.z = U * c[3] - W * c[2];   C.w = U * s[3] - W * s[2];   // F1

    float4* cp = (float4*)coefs;
    cp[(s0 * 3 + 0) * 64 + lane] = A;
    cp[(s0 * 3 + 1) * 64 + lane] = B;
    cp[(s0 * 3 + 2) * 64 + lane] = C;
}

// ---------- kernel 2: half-operator propagation (R12 machinery, 8 chunks) --
__global__ __launch_bounds__(64, 1)
void group_kernel(const float* __restrict__ thetas,  // [130,256]
                  const float* __restrict__ coefs,   // from k1
                  float* __restrict__ ws)            // P1/P2 blocks
{
    constexpr int N = 256;
    __shared__ float4 cbuf[2][1536];   // 2 x 24 KB (8-stage chunks)

    const int g    = blockIdx.x >> 8;    // 0: stages 1..64; 1: 65..128
    const int col  = blockIdx.x & 255;
    const int lane = threadIdx.x;

    const float BT = sqrtf(0.98f * 0.01f);
    const float BR = sqrtf(0.98f * 0.99f);
    const float eT0 = (lane == 0)  ? BR : BT, eR0 = (lane == 0)  ? 0.f : BR;
    const float eT3 = (lane == 63) ? BR : BT, eR3 = (lane == 63) ? 0.f : BR;

    float vr[4] = {0.f, 0.f, 0.f, 0.f};
    float vi[4] = {0.f, 0.f, 0.f, 0.f};

    // init: g=0 -> column of diag(exp(i*theta0)); g=1 -> identity column
    {
        const int r0 = col - 4 * lane;
        if (0 <= r0 && r0 < 4) {
            if (g == 0) {
                float s0, c0;
                __sincosf(thetas[col], &s0, &c0);
                vr[r0] = c0; vi[r0] = s0;
            } else {
                vr[r0] = 1.f;
            }
        }
    }

    float4 A0, B0, C0, A1, B1, C1, A2, B2, C2;
    auto rd2 = [&](int buf, int k) {
        const float4* p = &cbuf[buf][k * 192 + lane];
        A2 = p[0]; B2 = p[64]; C2 = p[128];
    };
    auto mstep = [&]() {
        {   // pair 1 first (ages vr[3] before crossing DPP)
            const float xr = vr[2], xi = vi[2], yr = vr[3], yi = vi[3];
            vr[2] = C0.x*xr - C0.y*xi + B0.z*yr - B0.w*yi;
            vi[2] = C0.x*xi + C0.y*xr + B0.z*yi + B0.w*yr;
            vr[3] = B0.z*xr - B0.w*xi + C0.z*yr - C0.w*yi;
            vi[3] = B0.z*xi + B0.w*xr + C0.z*yi + C0.w*yr;
        }
        {   // pair 0
            const float xr = vr[0], xi = vi[0], yr = vr[1], yi = vi[1];
            vr[0] = A0.x*xr - A0.y*xi + B0.x*yr - B0.y*yi;
            vi[0] = A0.x*xi + A0.y*xr + B0.x*yi + B0.y*yr;
            vr[1] = B0.x*xr - B0.y*xi + A0.z*yr - A0.w*yi;
            vi[1] = B0.x*xi + B0.y*xr + A0.z*yi + A0.w*yr;
        }
    };
    auto crossing = [&]() {
        const float pv3r = dpp_up1(vr[3]);
        const float pv3i = dpp_up1(vi[3]);
        const float nv0r = dpp_dn1(vr[0]);
        const float nv0i = dpp_dn1(vi[0]);
        {   // internal odd pair
            const float xr = vr[1], xi = vi[1], yr = vr[2], yi = vi[2];
            vr[1] = BT*xr - BR*yi;  vi[1] = BT*xi + BR*yr;
            vr[2] = BT*yr - BR*xi;  vi[2] = BT*yi + BR*xr;
        }
        vr[0] = eT0*vr[0] - eR0*pv3i;  vi[0] = eT0*vi[0] + eR0*pv3r;
        vr[3] = eT3*vr[3] - eR3*nv0i;  vi[3] = eT3*vi[3] + eR3*nv0r;
    };
    auto rotate = [&]() {
        A0 = A1; B0 = B1; C0 = C1;
        A1 = A2; B1 = B2; C1 = C2;
    };
    const int g8 = g * 8;   // chunk offset into coef table
    auto issue_chunk = [&](int c) {
        const float4* src = (const float4*)coefs + ((g8 + c) * 24) * 64 + lane;
        float4* dst = &cbuf[c & 1][0];
        #pragma unroll
        for (int j = 0; j < 24; ++j)
            __builtin_amdgcn_global_load_lds(
                (const __attribute__((address_space(1))) void*)(src + j * 64),
                (__attribute__((address_space(3))) void*)(dst + j * 64),
                16, 0, 0);
    };

    // prologue: chunks 0,1 in flight; chunk 0 landed
    issue_chunk(0);
    issue_chunk(1);
    asm volatile("s_waitcnt vmcnt(24)" ::: "memory");
    __builtin_amdgcn_sched_barrier(0);
    {
        const float4* p = &cbuf[0][lane];
        A0 = p[0]; B0 = p[64]; C0 = p[128];
        p = &cbuf[0][192 + lane];
        A1 = p[0]; B1 = p[64]; C1 = p[128];
    }

    // chunks 0..6 (8 stages each, all with crossing: local t=0..55)
    for (int c = 0; c < 7; ++c) {
        const int cb = c & 1;
        #pragma unroll
        for (int k = 0; k < 5; ++k) {
            rd2(cb, k + 2);
            mstep(); crossing(); rotate();
        }
        rd2(cb, 7);
        asm volatile("s_waitcnt lgkmcnt(0)" ::: "memory");
        __builtin_amdgcn_sched_barrier(0);
        if (c <= 5) {
            issue_chunk(c + 2);
            asm volatile("s_waitcnt vmcnt(24)" ::: "memory");
        } else {
            asm volatile("s_waitcnt vmcnt(0)" ::: "memory");   // chunk 7 landed
        }
        __builtin_amdgcn_sched_barrier(0);
        mstep(); crossing(); rotate();
        rd2(cb ^ 1, 0);
        mstep(); crossing(); rotate();
        rd2(cb ^ 1, 1);
        mstep(); crossing(); rotate();
    }

    // chunk 7 (buffer 1): local t=56..63
    #pragma unroll
    for (int k = 0; k < 6; ++k) {        // t=56..61
        rd2(1, k + 2);
        mstep(); crossing(); rotate();
    }
    mstep(); crossing(); rotate();       // t=62 (global 63 / 127: crossing)
    mstep();                             // t=63 (global 64 / 128)
    if (g == 0) crossing();              // s=64 has crossing; s=128 does not

    // g=1: fold D129 row phases (rows 4*lane..+3)
    if (g == 1) {
        float4 thF = *(const float4*)(thetas + 129 * N + 4 * lane);
        float sn[4], cs[4];
        sincos4(thF, sn, cs);
        #pragma unroll
        for (int j = 0; j < 4; ++j) {
            const float r = vr[j], i = vi[j];
            vr[j] = cs[j]*r - sn[j]*i;
            vi[j] = cs[j]*i + sn[j]*r;
        }
    }

    // store column col of P_g, col-major planar
    float* base = ws + 98304 + g * 131072;
    *(float4*)(base + col * 256 + 4 * lane) =
        make_float4(vr[0], vr[1], vr[2], vr[3]);
    *(float4*)(base + 65536 + col * 256 + 4 * lane) =
        make_float4(vi[0], vi[1], vi[2], vi[3]);
}

// ---------- kernel 3: M = P2 x P1 (256^3 complex), out planar row-major ----
__global__ __launch_bounds__(256)
void cgemm_kernel(const float* __restrict__ ws,
                  float* __restrict__ out)
{
    __shared__ float As_re[32][36], As_im[32][36];   // [kk][row], pad 36
    __shared__ float Bs_re[32][36], Bs_im[32][36];   // [kk][col]

    const int t  = threadIdx.x;          // 0..255
    const int bx = blockIdx.x;           // 0..63
    const int r0 = (bx & 7) * 32;        // tile row base
    const int c0 = (bx >> 3) * 32;       // tile col base
    const int tr = t & 15, tc = t >> 4;  // 16x16 thread grid, 2x2 each

    const float* Am = ws + 98304 + 131072;   // P2 (col-major planar)
    const float* Bm = ws + 98304;            // P1

    float accr[2][2] = {{0.f,0.f},{0.f,0.f}};
    float acci[2][2] = {{0.f,0.f},{0.f,0.f}};

    for (int k0 = 0; k0 < 256; k0 += 32) {
        {   // stage A tile: As[kk][row] = P2[r0+row, k0+kk]
            const int kk = t >> 3, r4 = 4 * (t & 7);
            const int ga = (k0 + kk) * 256 + r0 + r4;
            *(float4*)&As_re[kk][r4] = *(const float4*)(Am + ga);
            *(float4*)&As_im[kk][r4] = *(const float4*)(Am + 65536 + ga);
        }
        {   // stage B tile: Bs[kk][col] = P1[k0+kk, c0+col]
            const int cc = t & 31, kq = (t >> 5) * 4;
            const int gb = (c0 + cc) * 256 + k0 + kq;
            const float4 br = *(const float4*)(Bm + gb);
            const float4 bi = *(const float4*)(Bm + 65536 + gb);
            Bs_re[kq + 0][cc] = br.x;  Bs_im[kq + 0][cc] = bi.x;
            Bs_re[kq + 1][cc] = br.y;  Bs_im[kq + 1][cc] = bi.y;
            Bs_re[kq + 2][cc] = br.z;  Bs_im[kq + 2][cc] = bi.z;
            Bs_re[kq + 3][cc] = br.w;  Bs_im[kq + 3][cc] = bi.w;
        }
        __syncthreads();
        #pragma unroll 8
        for (int kk = 0; kk < 32; ++kk) {
            const float2 ar = *(const float2*)&As_re[kk][2 * tr];
            const float2 ai = *(const float2*)&As_im[kk][2 * tr];
            const float2 br = *(const float2*)&Bs_re[kk][2 * tc];
            const float2 bi = *(const float2*)&Bs_im[kk][2 * tc];
            accr[0][0] += ar.x*br.x - ai.x*bi.x;
            acci[0][0] += ar.x*bi.x + ai.x*br.x;
            accr[0][1] += ar.x*br.y - ai.x*bi.y;
            acci[0][1] += ar.x*bi.y + ai.x*br.y;
            accr[1][0] += ar.y*br.x - ai.y*bi.x;
            acci[1][0] += ar.y*bi.x + ai.y*br.x;
            accr[1][1] += ar.y*br.y - ai.y*bi.y;
            acci[1][1] += ar.y*bi.y + ai.y*br.y;
        }
        __syncthreads();
    }

    // out planar row-major: rows r0+2tr+i, cols c0+2tc+j
    #pragma unroll
    for (int i = 0; i < 2; ++i) {
        #pragma unroll
        for (int j = 0; j < 2; ++j) {
            const int idx = (r0 + 2*tr + i) * 256 + (c0 + 2*tc + j);
            out[idx]         = accr[i][j];
            out[65536 + idx] = acci[i][j];
        }
    }
}

extern "C" void kernel_launch(void* const* d_in, const int* in_sizes, int n_in,
                              void* d_out, int out_size, void* d_ws, size_t ws_size,
                              hipStream_t stream)
{
    const float* thetas = (const float*)d_in[0];   // [130,256] fp32
    float* out = (float*)d_out;                    // planar: re[65536] || im[65536]
    float* ws  = (float*)d_ws;
    (void)in_sizes; (void)n_in; (void)out_size; (void)ws_size;

    coef_kernel <<<dim3(128), dim3(64),  0, stream>>>(thetas, ws);
    group_kernel<<<dim3(512), dim3(64),  0, stream>>>(thetas, ws, ws);
    cgemm_kernel<<<dim3(64),  dim3(256), 0, stream>>>(ws, out);
}

// Round 12
// 73.924 us; speedup vs baseline: 1.7053x; 1.1803x over previous
//
#include <hip/hip_runtime.h>

// NEUROPULS unitary mesh, N=256 — R15: whole-chunk register hoist.
// R14 post-mortem: tree decomposition loses (combine GEMM + launches cost
// more than the shortened chain saves). Back to R12's monolithic structure.
// Closing the cycle model: R12 = 242 ns/stage = issue (~115cy) + ~one
// exposed LDS-read latency per stage at idle clock — the compiler sinks
// ds_reads to first use (lgkm analog of the documented vmcnt-drain mode),
// so the source-level distance-2 pipeline only partially hid it (-3.6us).
// Fix: per 8-stage chunk, load ALL coefs into 96 VGPRs (24 ds_read_b128,
// static indices), ONE lgkmcnt(0)+sched_barrier, issue next DMA chunk,
// then 8 stages of pure-register VALU (no LDS ops in the compute region:
// nothing to sink, nothing to wait on). LDS wait: ~120cy/chunk = 15cy/stage
// amortized; compute (~800cy) covers the in-flight DMA (vmcnt(24), never 0
// in-loop). Math identical to passing R12 (coef kernel, mstep, edge-const
// crossing, DMA chunk scheme).
// Coef layout (float4): [(stage*3+g)*64+lane], g in {A,B,C}:
//   A=(Er0,Ei0,Fr0,Fi0) B=(Gr0,Gi0,Gr1,Gi1) C=(Er1,Ei1,Fr1,Fi1)
//   E=U*p0-W*p1, F=U*p1-W*p0, G=i*g*(p0+p1); U=AT^2, W=AR^2, g=AT*AR.

__device__ __forceinline__ float dpp_up1(float x) {   // wave_shr:1, n <- n-1
    return __int_as_float(__builtin_amdgcn_update_dpp(
        __float_as_int(x), __float_as_int(x), 0x138, 0xf, 0xf, false));
}
__device__ __forceinline__ float dpp_dn1(float x) {   // wave_shl:1, n <- n+1
    return __int_as_float(__builtin_amdgcn_update_dpp(
        __float_as_int(x), __float_as_int(x), 0x130, 0xf, 0xf, false));
}
__device__ __forceinline__ void sincos4(float4 th, float sn[4], float cs[4]) {
    __sincosf(th.x, &sn[0], &cs[0]);
    __sincosf(th.y, &sn[1], &cs[1]);
    __sincosf(th.z, &sn[2], &cs[2]);
    __sincosf(th.w, &sn[3], &cs[3]);
}

// ---------- kernel 1: per-stage collapsed coefficients (R12, verified) ----
__global__ __launch_bounds__(64)
void coef_kernel(const float* __restrict__ thetas,  // [130,256]
                 float* __restrict__ coefs)         // 128*3*64 float4
{
    const int s0   = blockIdx.x;    // 0..127 -> theta row s0+1
    const int lane = threadIdx.x;   // 0..63

    const float U  = 0.98f * 0.505f;                  // AT^2
    const float W  = 0.98f * 0.495f;                  // AR^2
    const float Gc = 0.98f * sqrtf(0.505f * 0.495f);  // AT*AR

    float4 th = *(const float4*)(thetas + (s0 + 1) * 256 + 4 * lane);
    float s[4], c[4];
    sincos4(th, s, c);

    float4 A, B, C;
    A.x = U * c[0] - W * c[1];   A.y = U * s[0] - W * s[1];   // E0
    A.z = U * c[1] - W * c[0];   A.w = U * s[1] - W * s[0];   // F0
    B.x = -Gc * (s[0] + s[1]);   B.y = Gc * (c[0] + c[1]);    // G0
    B.z = -Gc * (s[2] + s[3]);   B.w = Gc * (c[2] + c[3]);    // G1
    C.x = U * c[2] - W * c[3];   C.y = U * s[2] - W * s[3];   // E1
    C.z = U * c[3] - W * c[2];   C.w = U * s[3] - W * s[2];   // F1

    float4* cp = (float4*)coefs;
    cp[(s0 * 3 + 0) * 64 + lane] = A;
    cp[(s0 * 3 + 1) * 64 + lane] = B;
    cp[(s0 * 3 + 2) * 64 + lane] = C;
}

// ---------- kernel 2: mesh state chain ----------
__global__ __launch_bounds__(64, 1)
void neuropuls_mesh_kernel(const float* __restrict__ thetas,  // [130,256]
                           const float* __restrict__ coefs,   // ws (from k1)
                           float* __restrict__ out)           // re[65536] || im[65536]
{
    constexpr int N = 256;
    // 16 chunks x 8 stages; per chunk 8*3*64 float4 = 24 KB; double-buffered.
    __shared__ float4 cbuf[2][1536];

    const int lane = threadIdx.x;   // 0..63
    const int col  = blockIdx.x;    // 0..255

    const float BT = sqrtf(0.98f * 0.01f);   // CR a*sqrt(CT)
    const float BR = sqrtf(0.98f * 0.99f);   // CR thru amplitude
    const float eT0 = (lane == 0)  ? BR : BT, eR0 = (lane == 0)  ? 0.f : BR;
    const float eT3 = (lane == 63) ? BR : BT, eR3 = (lane == 63) ? 0.f : BR;

    float vr[4] = {0.f, 0.f, 0.f, 0.f};
    float vi[4] = {0.f, 0.f, 0.f, 0.f};

    // arch0 = diag(exp(i*theta[0]))
    {
        const float th0 = thetas[col];
        float s0, c0;
        __sincosf(th0, &s0, &c0);
        const int r0 = col - 4 * lane;
        if (0 <= r0 && r0 < 4) { vr[r0] = c0; vi[r0] = s0; }
    }

    auto mstep = [&](const float4& A, const float4& B, const float4& C) {
        {   // pair 1 first (ages vr[3] before crossing DPP reads it)
            const float xr = vr[2], xi = vi[2], yr = vr[3], yi = vi[3];
            vr[2] = C.x*xr - C.y*xi + B.z*yr - B.w*yi;
            vi[2] = C.x*xi + C.y*xr + B.z*yi + B.w*yr;
            vr[3] = B.z*xr - B.w*xi + C.z*yr - C.w*yi;
            vi[3] = B.z*xi + B.w*xr + C.z*yi + C.w*yr;
        }
        {   // pair 0
            const float xr = vr[0], xi = vi[0], yr = vr[1], yi = vi[1];
            vr[0] = A.x*xr - A.y*xi + B.x*yr - B.y*yi;
            vi[0] = A.x*xi + A.y*xr + B.x*yi + B.y*yr;
            vr[1] = B.x*xr - B.y*xi + A.z*yr - A.w*yi;
            vi[1] = B.x*xi + B.y*xr + A.z*yi + A.w*yr;
        }
    };
    auto crossing = [&]() {
        const float pv3r = dpp_up1(vr[3]);
        const float pv3i = dpp_up1(vi[3]);
        const float nv0r = dpp_dn1(vr[0]);
        const float nv0i = dpp_dn1(vi[0]);
        {   // internal odd pair (4t+1, 4t+2)
            const float xr = vr[1], xi = vi[1], yr = vr[2], yi = vi[2];
            vr[1] = BT*xr - BR*yi;  vi[1] = BT*xi + BR*yr;
            vr[2] = BT*yr - BR*xi;  vi[2] = BT*yi + BR*xr;
        }
        // edge pairs via per-lane constants (thru lanes multiply DPP junk by 0)
        vr[0] = eT0*vr[0] - eR0*pv3i;  vi[0] = eT0*vi[0] + eR0*pv3r;
        vr[3] = eT3*vr[3] - eR3*nv0i;  vi[3] = eT3*vi[3] + eR3*nv0r;
    };

    // issue chunk c's 24 DMA segments (1 KB each) into cbuf[c&1]
    auto issue_chunk = [&](int c) {
        const float4* src = (const float4*)coefs + (c * 24) * 64 + lane;
        float4* dst = &cbuf[c & 1][0];
        #pragma unroll
        for (int j = 0; j < 24; ++j)
            __builtin_amdgcn_global_load_lds(
                (const __attribute__((address_space(1))) void*)(src + j * 64),
                (__attribute__((address_space(3))) void*)(dst + j * 64),
                16, 0, 0);
    };

    // ---- prologue: chunks 0,1 in flight; chunk 0 landed after vmcnt(24) ----
    issue_chunk(0);
    issue_chunk(1);
    asm volatile("s_waitcnt vmcnt(24)" ::: "memory");
    __builtin_amdgcn_sched_barrier(0);

    // chunks 0..14 (stages s = 8c+1 .. 8c+8, all with crossing: s <= 120)
    for (int c = 0; c < 15; ++c) {
        const int cb = c & 1;
        // hoist the whole chunk's coefs into registers (static indices)
        float4 KA[8], KB[8], KC[8];
        #pragma unroll
        for (int k = 0; k < 8; ++k) {
            const float4* p = &cbuf[cb][k * 192 + lane];
            KA[k] = p[0]; KB[k] = p[64]; KC[k] = p[128];
        }
        asm volatile("s_waitcnt lgkmcnt(0)" ::: "memory");   // reads done;
        __builtin_amdgcn_sched_barrier(0);                   // cbuf[cb] free
        if (c <= 13) issue_chunk(c + 2);                     // refill cbuf[cb]
        // ---- 8 stages of pure-register compute (no LDS ops) ----
        #pragma unroll
        for (int k = 0; k < 8; ++k) {
            mstep(KA[k], KB[k], KC[k]);
            crossing();
        }
        // gate: chunk c+1 fully landed before next iteration reads it
        if (c <= 13)
            asm volatile("s_waitcnt vmcnt(24)" ::: "memory");
        else
            asm volatile("s_waitcnt vmcnt(0)" ::: "memory"); // chunk 15 landed
        __builtin_amdgcn_sched_barrier(0);
    }

    // chunk 15 (buffer 1): stages s = 121..128; s=128 has no crossing
    {
        float4 KA[8], KB[8], KC[8];
        #pragma unroll
        for (int k = 0; k < 8; ++k) {
            const float4* p = &cbuf[1][k * 192 + lane];
            KA[k] = p[0]; KB[k] = p[64]; KC[k] = p[128];
        }
        asm volatile("s_waitcnt lgkmcnt(0)" ::: "memory");
        __builtin_amdgcn_sched_barrier(0);
        #pragma unroll
        for (int k = 0; k < 7; ++k) {      // s = 121..127
            mstep(KA[k], KB[k], KC[k]);
            crossing();
        }
        mstep(KA[7], KB[7], KC[7]);        // s = 128: mstep only
    }

    // final phase layer theta[129] (global, one-time)
    {
        float4 thF = *(const float4*)(thetas + 129 * N + 4 * lane);
        float sn[4], cs[4];
        sincos4(thF, sn, cs);
        #pragma unroll
        for (int j = 0; j < 4; ++j) {
            const float r = vr[j], i = vi[j];
            vr[j] = cs[j]*r - sn[j]*i;
            vi[j] = cs[j]*i + sn[j]*r;
        }
    }

    // store PLANAR: real block then imag block, row-major [row][col]
    #pragma unroll
    for (int j = 0; j < 4; ++j) {
        const int idx = (4 * lane + j) * N + col;
        out[idx]         = vr[j];
        out[N * N + idx] = vi[j];
    }
}

extern "C" void kernel_launch(void* const* d_in, const int* in_sizes, int n_in,
                              void* d_out, int out_size, void* d_ws, size_t ws_size,
                              hipStream_t stream)
{
    const float* thetas = (const float*)d_in[0];   // [130,256] fp32
    float* out   = (float*)d_out;                  // planar: re[65536] || im[65536]
    float* coefs = (float*)d_ws;                   // 128*3*64 float4 = 384 KB
    (void)in_sizes; (void)n_in; (void)out_size; (void)ws_size;

    coef_kernel<<<dim3(128), dim3(64), 0, stream>>>(thetas, coefs);
    neuropuls_mesh_kernel<<<dim3(256), dim3(64), 0, stream>>>(thetas, coefs, out);
}

// Round 13
// 71.826 us; speedup vs baseline: 1.7551x; 1.0292x over previous
//
#include <hip/hip_runtime.h>

// NEUROPULS unitary mesh, N=256 — R16: packed-FP32 compute core.
// R15 post-mortem: LDS/vmem latency theories all dead (R12==R15==74us).
// Surviving model: per-stage wall ~240cy at idle clock = issue (~120cy,
// ~60 wave64 VALU ops) + chain/cadence stall. Lever: halve the issue.
// gfx950 has dual-rate packed fp32 (v_pk_fma_f32 — the 157.3TF spec IS
// 2x the 78.6TF scalar ceiling). One pk op with op_sel/neg_lo does both
// halves of a complex MAC:
//   cmul K(x)z: t=pk_mul(K.lo bcast, z); t=pk_fma(K.hi bcast, z.swap, t)
//               neg_lo[S0]  ->  [Kr*zr-Ki*zi, Kr*zi+Ki*zr]
// mstep: 16 pk (was 32 FMA); crossing: 8 pk (was ~12+cndmask); DPP x4.
// All staging machinery (coef kernel, 8-stage DMA chunks, whole-chunk
// hoist, counted vmcnt) verbatim from R15 (passed R12..R15).
// Coef layout (float4): [(stage*3+g)*64+lane], g in {A,B,C}:
//   A=(Er0,Ei0,Fr0,Fi0) B=(Gr0,Gi0,Gr1,Gi1) C=(Er1,Ei1,Fr1,Fi1)
//   E=U*p0-W*p1, F=U*p1-W*p0, G=i*g*(p0+p1); U=AT^2, W=AR^2, g=AT*AR.

__device__ __forceinline__ float dpp_up1(float x) {   // wave_shr:1, n <- n-1
    return __int_as_float(__builtin_amdgcn_update_dpp(
        __float_as_int(x), __float_as_int(x), 0x138, 0xf, 0xf, false));
}
__device__ __forceinline__ float dpp_dn1(float x) {   // wave_shl:1, n <- n+1
    return __int_as_float(__builtin_amdgcn_update_dpp(
        __float_as_int(x), __float_as_int(x), 0x130, 0xf, 0xf, false));
}
__device__ __forceinline__ void sincos4(float4 th, float sn[4], float cs[4]) {
    __sincosf(th.x, &sn[0], &cs[0]);
    __sincosf(th.y, &sn[1], &cs[1]);
    __sincosf(th.z, &sn[2], &cs[2]);
    __sincosf(th.w, &sn[3], &cs[3]);
}

// t = K (x) z  (complex mul, z=[re,im], K=[Kr,Ki]) — 2 pk ops
__device__ __forceinline__ float2 cmul_pk(float2 K, float2 z) {
    float2 t;
    asm("v_pk_mul_f32 %0, %1, %2 op_sel:[0,0] op_sel_hi:[0,1]\n\t"
        "v_pk_fma_f32 %0, %1, %2, %0 op_sel:[1,1,0] op_sel_hi:[1,0,1] neg_lo:[1,0,0]"
        : "=&v"(t) : "v"(K), "v"(z));
    return t;
}
// acc += K (x) z — 2 pk ops
__device__ __forceinline__ float2 cfma_pk(float2 K, float2 z, float2 acc) {
    asm("v_pk_fma_f32 %0, %1, %2, %0 op_sel:[0,0,0] op_sel_hi:[0,1,1]\n\t"
        "v_pk_fma_f32 %0, %1, %2, %0 op_sel:[1,1,0] op_sel_hi:[1,0,1] neg_lo:[1,0,0]"
        : "+v"(acc) : "v"(K), "v"(z));
    return acc;
}
// t = [K.lo*z.re - K.hi*p.im, K.lo*z.im + K.hi*p.re]  (crossing row) — 2 pk
__device__ __forceinline__ float2 cross_pk(float2 K, float2 z, float2 p) {
    float2 t;
    asm("v_pk_mul_f32 %0, %1, %2 op_sel:[0,0] op_sel_hi:[0,1]\n\t"
        "v_pk_fma_f32 %0, %1, %3, %0 op_sel:[1,1,0] op_sel_hi:[1,0,1] neg_lo:[1,0,0]"
        : "=&v"(t) : "v"(K), "v"(z), "v"(p));
    return t;
}

// ---------- kernel 1: per-stage collapsed coefficients (verified) ----------
__global__ __launch_bounds__(64)
void coef_kernel(const float* __restrict__ thetas,  // [130,256]
                 float* __restrict__ coefs)         // 128*3*64 float4
{
    const int s0   = blockIdx.x;    // 0..127 -> theta row s0+1
    const int lane = threadIdx.x;   // 0..63

    const float U  = 0.98f * 0.505f;                  // AT^2
    const float W  = 0.98f * 0.495f;                  // AR^2
    const float Gc = 0.98f * sqrtf(0.505f * 0.495f);  // AT*AR

    float4 th = *(const float4*)(thetas + (s0 + 1) * 256 + 4 * lane);
    float s[4], c[4];
    sincos4(th, s, c);

    float4 A, B, C;
    A.x = U * c[0] - W * c[1];   A.y = U * s[0] - W * s[1];   // E0
    A.z = U * c[1] - W * c[0];   A.w = U * s[1] - W * s[0];   // F0
    B.x = -Gc * (s[0] + s[1]);   B.y = Gc * (c[0] + c[1]);    // G0
    B.z = -Gc * (s[2] + s[3]);   B.w = Gc * (c[2] + c[3]);    // G1
    C.x = U * c[2] - W * c[3];   C.y = U * s[2] - W * s[3];   // E1
    C.z = U * c[3] - W * c[2];   C.w = U * s[3] - W * s[2];   // F1

    float4* cp = (float4*)coefs;
    cp[(s0 * 3 + 0) * 64 + lane] = A;
    cp[(s0 * 3 + 1) * 64 + lane] = B;
    cp[(s0 * 3 + 2) * 64 + lane] = C;
}

// ---------- kernel 2: mesh state chain (packed core) ----------
__global__ __launch_bounds__(64, 1)
void neuropuls_mesh_kernel(const float* __restrict__ thetas,  // [130,256]
                           const float* __restrict__ coefs,   // ws (from k1)
                           float* __restrict__ out)           // re[65536] || im[65536]
{
    constexpr int N = 256;
    __shared__ float4 cbuf[2][1536];   // 2 x 24 KB (8-stage chunks)

    const int lane = threadIdx.x;   // 0..63
    const int col  = blockIdx.x;    // 0..255

    const float BT = sqrtf(0.98f * 0.01f);   // CR a*sqrt(CT)
    const float BR = sqrtf(0.98f * 0.99f);   // CR thru amplitude
    const float2 CK  = make_float2(BT, BR);
    const float2 EC0 = (lane == 0)  ? make_float2(BR, 0.f) : CK;  // row 0 thru
    const float2 EC3 = (lane == 63) ? make_float2(BR, 0.f) : CK;  // row 255 thru

    // state: rows 4*lane..4*lane+3 of the current column, packed [re,im]
    float2 z0 = make_float2(0.f, 0.f), z1 = z0, z2 = z0, z3 = z0;

    // arch0 = diag(exp(i*theta[0]))
    {
        const float th0 = thetas[col];
        float s0, c0;
        __sincosf(th0, &s0, &c0);
        const int r0 = col - 4 * lane;
        if (r0 == 0) z0 = make_float2(c0, s0);
        else if (r0 == 1) z1 = make_float2(c0, s0);
        else if (r0 == 2) z2 = make_float2(c0, s0);
        else if (r0 == 3) z3 = make_float2(c0, s0);
    }

    // mstep: x'=E(x)x + G(x)y ; y'=G(x)x + F(x)y per pair — 16 pk ops
    auto mstep = [&](const float4& KA, const float4& KB, const float4& KC) {
        const float2 E0 = make_float2(KA.x, KA.y), F0 = make_float2(KA.z, KA.w);
        const float2 G0 = make_float2(KB.x, KB.y), G1 = make_float2(KB.z, KB.w);
        const float2 E1 = make_float2(KC.x, KC.y), F1 = make_float2(KC.z, KC.w);
        const float2 nx0 = cfma_pk(G0, z1, cmul_pk(E0, z0));
        const float2 ny0 = cfma_pk(F0, z1, cmul_pk(G0, z0));
        const float2 nx1 = cfma_pk(G1, z3, cmul_pk(E1, z2));
        const float2 ny1 = cfma_pk(F1, z3, cmul_pk(G1, z2));
        z0 = nx0; z1 = ny0; z2 = nx1; z3 = ny1;
    };
    // crossing — 8 pk + 4 DPP
    auto crossing = [&]() {
        const float2 pv3 = make_float2(dpp_up1(z3.x), dpp_up1(z3.y));
        const float2 nv0 = make_float2(dpp_dn1(z0.x), dpp_dn1(z0.y));
        const float2 t1 = cross_pk(CK, z1, z2);
        const float2 t2 = cross_pk(CK, z2, z1);
        z0 = cross_pk(EC0, z0, pv3);
        z3 = cross_pk(EC3, z3, nv0);
        z1 = t1; z2 = t2;
    };

    // issue chunk c's 24 DMA segments (1 KB each) into cbuf[c&1]
    auto issue_chunk = [&](int c) {
        const float4* src = (const float4*)coefs + (c * 24) * 64 + lane;
        float4* dst = &cbuf[c & 1][0];
        #pragma unroll
        for (int j = 0; j < 24; ++j)
            __builtin_amdgcn_global_load_lds(
                (const __attribute__((address_space(1))) void*)(src + j * 64),
                (__attribute__((address_space(3))) void*)(dst + j * 64),
                16, 0, 0);
    };

    // ---- prologue: chunks 0,1 in flight; chunk 0 landed after vmcnt(24) ----
    issue_chunk(0);
    issue_chunk(1);
    asm volatile("s_waitcnt vmcnt(24)" ::: "memory");
    __builtin_amdgcn_sched_barrier(0);

    // chunks 0..14 (stages s = 8c+1 .. 8c+8, all with crossing: s <= 120)
    for (int c = 0; c < 15; ++c) {
        const int cb = c & 1;
        // hoist the whole chunk's coefs into registers (static indices)
        float4 KA[8], KB[8], KC[8];
        #pragma unroll
        for (int k = 0; k < 8; ++k) {
            const float4* p = &cbuf[cb][k * 192 + lane];
            KA[k] = p[0]; KB[k] = p[64]; KC[k] = p[128];
        }
        asm volatile("s_waitcnt lgkmcnt(0)" ::: "memory");   // reads done;
        __builtin_amdgcn_sched_barrier(0);                   // cbuf[cb] free
        if (c <= 13) issue_chunk(c + 2);                     // refill cbuf[cb]
        // ---- 8 stages of pure-register packed compute ----
        #pragma unroll
        for (int k = 0; k < 8; ++k) {
            mstep(KA[k], KB[k], KC[k]);
            crossing();
        }
        // gate: chunk c+1 fully landed before next iteration reads it
        if (c <= 13)
            asm volatile("s_waitcnt vmcnt(24)" ::: "memory");
        else
            asm volatile("s_waitcnt vmcnt(0)" ::: "memory"); // chunk 15 landed
        __builtin_amdgcn_sched_barrier(0);
    }

    // chunk 15 (buffer 1): stages s = 121..128; s=128 has no crossing
    {
        float4 KA[8], KB[8], KC[8];
        #pragma unroll
        for (int k = 0; k < 8; ++k) {
            const float4* p = &cbuf[1][k * 192 + lane];
            KA[k] = p[0]; KB[k] = p[64]; KC[k] = p[128];
        }
        asm volatile("s_waitcnt lgkmcnt(0)" ::: "memory");
        __builtin_amdgcn_sched_barrier(0);
        #pragma unroll
        for (int k = 0; k < 7; ++k) {      // s = 121..127
            mstep(KA[k], KB[k], KC[k]);
            crossing();
        }
        mstep(KA[7], KB[7], KC[7]);        // s = 128: mstep only
    }

    // final phase layer theta[129]: z *= exp(i*th) — complex mul
    {
        float4 thF = *(const float4*)(thetas + 129 * N + 4 * lane);
        float sn[4], cs[4];
        sincos4(thF, sn, cs);
        z0 = cmul_pk(make_float2(cs[0], sn[0]), z0);
        z1 = cmul_pk(make_float2(cs[1], sn[1]), z1);
        z2 = cmul_pk(make_float2(cs[2], sn[2]), z2);
        z3 = cmul_pk(make_float2(cs[3], sn[3]), z3);
    }

    // store PLANAR: real block then imag block, row-major [row][col]
    {
        const int r = 4 * lane;
        out[(r + 0) * N + col] = z0.x;  out[N * N + (r + 0) * N + col] = z0.y;
        out[(r + 1) * N + col] = z1.x;  out[N * N + (r + 1) * N + col] = z1.y;
        out[(r + 2) * N + col] = z2.x;  out[N * N + (r + 2) * N + col] = z2.y;
        out[(r + 3) * N + col] = z3.x;  out[N * N + (r + 3) * N + col] = z3.y;
    }
}

extern "C" void kernel_launch(void* const* d_in, const int* in_sizes, int n_in,
                              void* d_out, int out_size, void* d_ws, size_t ws_size,
                              hipStream_t stream)
{
    const float* thetas = (const float*)d_in[0];   // [130,256] fp32
    float* out   = (float*)d_out;                  // planar: re[65536] || im[65536]
    float* coefs = (float*)d_ws;                   // 128*3*64 float4 = 384 KB
    (void)in_sizes; (void)n_in; (void)out_size; (void)ws_size;

    coef_kernel<<<dim3(128), dim3(64), 0, stream>>>(thetas, coefs);
    neuropuls_mesh_kernel<<<dim3(256), dim3(64), 0, stream>>>(thetas, coefs, out);
}